// Round 7
// baseline (151.525 us; speedup 1.0000x reference)
//
#include <hip/hip_runtime.h>

static constexpr float kIouT = 0.35f;
static constexpr float kScoreT = 0.5f;
static constexpr int kMaxNW = 40;     // scan fast path supports m <= 40*64 = 2560
static constexpr int kStrideW = 40;   // LDS row stride (u64 words)
static constexpr int kDepth = 3;      // triple-buffered chunk pipeline
static constexpr int kProdWaves = 7;  // waves 1..7 produce, wave 0 consumes
static constexpr int kRowsPW = 10;    // ceil(64/7) rows per producer wave
static constexpr int kMaxKeep = 512;

// Bit-exact mirror of the reference IoU (no FMA contraction).
__device__ __forceinline__ float iou_f(const float4 a, const float4 b) {
  float areaA = __fmul_rn(a.z - a.x, a.w - a.y);
  float areaB = __fmul_rn(b.z - b.x, b.w - b.y);
  float iy1 = fmaxf(a.x, b.x);
  float ix1 = fmaxf(a.y, b.y);
  float iy2 = fminf(a.z, b.z);
  float ix2 = fminf(a.w, b.w);
  float dy = fmaxf(iy2 - iy1, 0.0f);
  float dx = fmaxf(ix2 - ix1, 0.0f);
  float inter = __fmul_rn(dy, dx);
  float uni = (areaA + areaB) - inter;
  return (uni > 0.0f) ? __fdiv_rn(inter, uni) : 0.0f;
}

// 64-bit cross-lane pull with UNIFORM lane index (v_readlane, no LDS crossbar).
__device__ __forceinline__ unsigned long long rdlane64(unsigned long long v,
                                                       int l) {
  unsigned lo = (unsigned)__builtin_amdgcn_readlane((int)(unsigned)v, l);
  unsigned hi = (unsigned)__builtin_amdgcn_readlane((int)(unsigned)(v >> 32), l);
  return ((unsigned long long)hi << 32) | lo;
}

// ------- kernel 1 — rank (counting) sort, LDS-staged scores (+count fold) ----
// Blocks [0, rankBlocks): 64 rows per block; the image's score array is staged
// once into LDS (16 KB), then 16 waves x 4 rows rank from LDS. L2 traffic
// drops 512 MB -> ~8 MB. rank = #{j: s_j > s_i} + #{j: s_j==s_i, j<i}; invalid
// j (s<=0.5) sort after every valid i, so counting over ALL j is exact.
// Blocks [rankBlocks, rankBlocks+B): per-image valid count -> Mcnt.
__global__ __launch_bounds__(1024)
void nms_rank_kernel(const float* __restrict__ scores,
                     const float4* __restrict__ boxes,
                     unsigned long long* __restrict__ skeys,
                     float4* __restrict__ sboxes,
                     int* __restrict__ Mcnt, int N, int rankBlocks) {
  const int tid = threadIdx.x;
  const int lane = tid & 63;
  const int wv = tid >> 6;
  if ((int)blockIdx.x >= rankBlocks) {   // ---- count mode ----
    __shared__ int part[16];
    const int img = blockIdx.x - rankBlocks;
    const float4* sc4 = (const float4*)(scores + (size_t)img * N);
    int c = 0;
    for (int q = tid; q < (N >> 2); q += 1024) {
      float4 v = sc4[q];
      c += (v.x > kScoreT) + (v.y > kScoreT) + (v.z > kScoreT) + (v.w > kScoreT);
    }
#pragma unroll
    for (int off = 1; off < 64; off <<= 1) c += __shfl_xor(c, off, 64);
    if (lane == 0) part[wv] = c;
    __syncthreads();
    if (tid == 0) {
      int s = 0;
      for (int k = 0; k < 16; ++k) s += part[k];
      Mcnt[img] = s;
    }
    return;
  }
  // ---- rank mode: 64 rows per block ----
  __shared__ __align__(16) float ssc[4096];
  const int wpb = N >> 6;                       // row-blocks per image
  const int img = blockIdx.x / wpb;
  const int rowbase = (blockIdx.x - img * wpb) << 6;
  const float* sc = scores + (size_t)img * N;
  for (int q = tid; q < N; q += 1024) ssc[q] = sc[q];
  __syncthreads();
  const float4* s4 = (const float4*)ssc;
#pragma unroll
  for (int rr = 0; rr < 4; ++rr) {
    const int row = rowbase + (wv << 2) + rr;
    const float si = ssc[row];
    if (!(si > kScoreT)) continue;              // wave-uniform branch
    int cnt = 0;
    for (int q = lane; q < (N >> 2); q += 64) {
      const float4 v = s4[q];
      const int j = q << 2;
      cnt += (v.x > si) + (v.y > si) + (v.z > si) + (v.w > si);
      if (v.x == si && j < row) cnt++;
      if (v.y == si && j + 1 < row) cnt++;
      if (v.z == si && j + 2 < row) cnt++;
      if (v.w == si && j + 3 < row) cnt++;
    }
#pragma unroll
    for (int off = 1; off < 64; off <<= 1) cnt += __shfl_xor(cnt, off, 64);
    if (lane == 0) {
      skeys[(size_t)img * N + cnt] =
          ((unsigned long long)(~__float_as_uint(si)) << 32) | (unsigned)row;
      sboxes[(size_t)img * N + cnt] = boxes[(size_t)img * N + row];
    }
  }
}

// ------------- kernel 2 — IoU suppression masks, LDS-staged boxes ------------
// 64 rows per block; stages sboxes[rowbase..m) into LDS once (<=64 KB), then
// 16 waves x 4 rows compute ballots from LDS. All rows in a block share the
// same starting word (rowbase multiple of 64).
__global__ __launch_bounds__(1024)
void nms_mask_kernel(const float4* __restrict__ sboxes,
                     const int* __restrict__ Mcnt,
                     unsigned long long* __restrict__ mask, int N) {
  __shared__ float4 ssb[4096];
  const int tid = threadIdx.x;
  const int lane = tid & 63;
  const int wv = tid >> 6;
  const int wpb = N >> 6;
  const int img = blockIdx.x / wpb;
  const int rowbase = (blockIdx.x - img * wpb) << 6;
  const int m = Mcnt[img];
  if (rowbase >= m) return;                 // block-uniform
  const int cnt = m - rowbase;              // staged entries
  const int nw = (m + 63) >> 6;
  const int wb = rowbase >> 6;
  const int stride = N >> 6;
  const float4* sb = sboxes + (size_t)img * N + rowbase;
  for (int q = tid; q < cnt; q += 1024) ssb[q] = sb[q];
  __syncthreads();
#pragma unroll
  for (int rr = 0; rr < 4; ++rr) {
    const int rl = (wv << 2) + rr;          // local row
    if (rl >= cnt) continue;
    const float4 bi = ssb[rl];
    unsigned long long* mrow =
        mask + (size_t)(img * N + rowbase + rl) * stride;
    for (int w = wb; w < nw; ++w) {
      const int jl = ((w - wb) << 6) | lane;
      bool sup = false;
      if (jl > rl && jl < cnt) sup = iou_f(bi, ssb[jl]) > kIouT;
      const unsigned long long bm = __ballot(sup);
      if (lane == 0) mrow[w] = bm;
    }
  }
}

// ------- kernel 3 — scan: 7 producer waves -> LDS, scalar readlane consumer ---
// Period c: consumer (wave 0) scans chunk c; producers commit chunk c+1 into
// LDS (loads issued at period c-1: full-period latency tolerance) and issue
// chunk c+2. Producers' lane 0 also deposits each row's diag word (word c of
// row c*64+r) into dbuf for a conflict-free consumer read. Consumer keep-chain
// is pure SALU/readlane (~40cy/keep); delta applies kept rows' word-lane from
// LDS (row-contiguous ds_reads, pipelined, off-chain). No global load on the
// consumer's critical path.
__global__ __launch_bounds__(512)
void nms_scan_kernel(const unsigned long long* __restrict__ skeys,
                     const float4* __restrict__ sboxes,
                     const int* __restrict__ Mcnt,
                     const unsigned long long* __restrict__ mask,
                     const float* __restrict__ anchors,
                     float* __restrict__ out, int N, int NS) {
  __shared__ unsigned long long lbuf[kDepth][64][kStrideW];  // 60 KiB
  __shared__ unsigned long long dbuf[kDepth][64];            // diag words
  __shared__ int keptlist[kMaxKeep];
  __shared__ int s_done, s_kept;
  const int img = blockIdx.x;
  const int tid = threadIdx.x;
  const int lane = tid & 63;
  const int wv = tid >> 6;
  int m = Mcnt[img];
  if (m > N) m = N;
  const int nw = (m + 63) >> 6;
  const int stride = N >> 6;
  const unsigned long long* mbase = mask + (size_t)img * (size_t)N * stride;
  const unsigned long long* kg = skeys + (size_t)img * N;
  const float4* sb = sboxes + (size_t)img * N;
  const float* an = anchors + (size_t)img * (size_t)N * 4;
  float* o = out + (size_t)img * NS * 7;
  if (tid == 0) { s_done = 0; s_kept = 0; }

  int kept = 0;
  unsigned long long remv = 0ull;

  if (m > 0 && nw <= kMaxNW) {
    const int pw = wv - 1;               // producer wave id 0..6
    unsigned long long pv[kRowsPW];      // in-flight chunk (static idx only)
    auto issue = [&](int cc) {
      if (cc >= nw) return;
      const int base = cc << 6;
      const int rlim = min(m - base, 64);
      const int w = cc + lane;
      const bool wok = (w < nw);
#pragma unroll
      for (int k = 0; k < kRowsPW; ++k) {
        const int r = pw + k * kProdWaves;
        if (r < rlim && wok) pv[k] = mbase[(size_t)(base + r) * stride + w];
      }
    };
    auto commit = [&](int cc) {
      if (cc >= nw) return;
      const int base = cc << 6;
      const int rlim = min(m - base, 64);
      const int w = cc + lane;
      const bool wok = (w < nw);
      const int bufi = cc % kDepth;
#pragma unroll
      for (int k = 0; k < kRowsPW; ++k) {
        const int r = pw + k * kProdWaves;
        if (r < rlim && wok) {
          lbuf[bufi][r][w - cc] = pv[k];          // store words cc.. at col 0..
          if (lane == 0) dbuf[bufi][r] = pv[k];   // lane 0 holds word cc (diag)
        }
      }
    };
    if (wv != 0) { issue(0); commit(0); issue(1); }
    __syncthreads();
    for (int c = 0; c < nw; ++c) {
      if (wv == 0) {
        const int bufi = c % kDepth;
        const int cb = c << 6;
        const unsigned long long diag = dbuf[bufi][lane];
        unsigned long long local = rdlane64(remv, c);
        const int rem = m - cb;
        unsigned long long avail = ~local;
        if (rem < 64) avail &= (1ull << rem) - 1ull;
        unsigned long long keptbits = 0ull;
        // serial greedy loop: SALU + readlane only
        while (avail != 0ull && kept < NS) {
          const int b = (int)__builtin_ctzll(avail);
          if (lane == 0) keptlist[kept] = cb + b;
          kept++;
          keptbits |= 1ull << b;
          const unsigned long long rc = rdlane64(diag, b);
          local |= rc;
          avail &= ~local;
          avail &= ~(1ull << b);
        }
        // delta: kept rows' word-lane from LDS (off the serial chain)
        const bool lok = (lane > c) && (lane < nw);
        const int widx = lok ? (lane - c) : 0;    // stored column
        unsigned long long kb = keptbits;
        while (kb != 0ull) {
          const int b = (int)__builtin_ctzll(kb);
          kb &= kb - 1ull;
          const unsigned long long t = lbuf[bufi][b][widx];
          if (lok) remv |= t;
        }
        if (lane == 0 && kept >= NS) s_done = 1;
      } else {
        commit(c + 1);   // loads issued one full period ago
        issue(c + 2);
      }
      __syncthreads();
      if (s_done != 0) break;
    }
  } else if (m > 0) {
    // safety fallback (m > 2560): wave 0 only, per-keep global mask rows.
    if (wv == 0) {
      for (int i = 0; i < m && kept < NS; ++i) {
        const unsigned long long rw = rdlane64(remv, i >> 6);
        if ((rw >> (i & 63)) & 1ull) continue;
        if (lane == 0) keptlist[kept] = i;
        kept++;
        const unsigned long long* mrow = mbase + (size_t)i * stride;
        if (lane >= (i >> 6) && lane < nw) remv |= mrow[lane];
      }
    }
  }

  if (wv == 0 && lane == 0) s_kept = kept;
  __syncthreads();
  const int K = s_kept;
  // parallel output: 512 threads over K kept rows
  for (int t = tid; t < K; t += 512) {
    const int i = keptlist[t];
    const unsigned long long ki = kg[i];
    const float4 bi = sb[i];
    const unsigned idx = (unsigned)ki;
    float* row = o + t * 7;
    row[0] = __uint_as_float(~(unsigned)(ki >> 32));
    row[1] = bi.x; row[2] = bi.y; row[3] = bi.z; row[4] = bi.w;
    row[5] = an[idx * 4 + 2];
    row[6] = an[idx * 4 + 3];
  }
  for (int t = K * 7 + tid; t < NS * 7; t += 512) o[t] = 0.0f;
}

// --------------- fallback: fused sort + on-the-fly scan (no d_ws) -------------
__global__ __launch_bounds__(1024)
void nms_fused_kernel(const float* __restrict__ scores,
                      const float4* __restrict__ boxes,
                      const float* __restrict__ anchors,
                      float* __restrict__ out, int N, int NS) {
  __shared__ unsigned long long keys[4096];
  __shared__ int s_m;
  if (N > 4096) return;
  const int img = blockIdx.x;
  const int tid = threadIdx.x;
  const float* sc = scores + (size_t)img * N;
  const float4* bx = boxes + (size_t)img * N;
  if (tid == 0) s_m = 0;
  __syncthreads();
  int cnt = 0;
  for (int i = tid; i < N; i += blockDim.x) {
    float s = sc[i];
    keys[i] = ((unsigned long long)(~__float_as_uint(s)) << 32) | (unsigned)i;
    if (s > kScoreT) cnt++;
  }
  if (cnt) atomicAdd(&s_m, cnt);
  __syncthreads();
  for (int k = 2; k <= N; k <<= 1) {
    for (int j = k >> 1; j > 0; j >>= 1) {
      for (int i = tid; i < N; i += blockDim.x) {
        int ixj = i ^ j;
        if (ixj > i) {
          unsigned long long a = keys[i];
          unsigned long long b = keys[ixj];
          bool up = ((i & k) == 0);
          if (up ? (a > b) : (a < b)) { keys[i] = b; keys[ixj] = a; }
        }
      }
      __syncthreads();
    }
  }
  if (tid >= 64) return;
  const int lane = tid;
  const int m = s_m;
  const int nw = (m + 63) >> 6;
  const float* an = anchors + (size_t)img * N * 4;
  float* o = out + (size_t)img * NS * 7;
  unsigned long long remv = 0ull;
  int kept = 0;
  for (int i = 0; i < m && kept < NS; ++i) {
    unsigned long long rw = __shfl(remv, i >> 6, 64);
    if ((rw >> (i & 63)) & 1ull) continue;
    unsigned long long ki = keys[i];
    float4 bi = bx[(unsigned)ki];
    if (lane == 0) {
      unsigned idx = (unsigned)ki;
      float* row = o + kept * 7;
      row[0] = __uint_as_float(~(unsigned)(ki >> 32));
      row[1] = bi.x; row[2] = bi.y; row[3] = bi.z; row[4] = bi.w;
      row[5] = an[idx * 4 + 2];
      row[6] = an[idx * 4 + 3];
    }
    kept++;
    for (int w2 = i >> 6; w2 < nw; ++w2) {
      int j = (w2 << 6) | lane;
      bool sup = false;
      if (j > i && j < m) sup = iou_f(bi, bx[(unsigned)keys[j]]) > kIouT;
      unsigned long long bm = __ballot(sup);
      if (lane == w2) remv |= bm;
    }
  }
  for (int t = kept * 7 + lane; t < NS * 7; t += 64) o[t] = 0.0f;
}

extern "C" void kernel_launch(void* const* d_in, const int* in_sizes, int n_in,
                              void* d_out, int out_size, void* d_ws, size_t ws_size,
                              hipStream_t stream) {
  const float* scores = (const float*)d_in[0];
  const float4* boxes = (const float4*)d_in[1];
  const float* anchors = (const float*)d_in[2];
  float* out = (float*)d_out;
  const int B = 8;
  const int N = in_sizes[0] / B;      // 4096 boxes/image
  const int NS = out_size / (B * 7);  // 300 samples

  const size_t nTot = (size_t)B * (size_t)N;
  const size_t keysB = nTot * 8;
  const size_t sboxB = nTot * 16;
  const size_t mcntB = 256;
  const size_t maskB = nTot * (size_t)(N >> 6) * 8;
  const size_t need = keysB + sboxB + mcntB + maskB;

  if (ws_size >= need && (N % 256) == 0 && N >= 256 && N <= 4096 &&
      NS <= kMaxKeep) {
    char* p = (char*)d_ws;
    unsigned long long* skeys = (unsigned long long*)p; p += keysB;
    float4* sboxes = (float4*)p;                         p += sboxB;
    int* Mcnt = (int*)p;                                 p += mcntB;
    unsigned long long* mask = (unsigned long long*)p;

    const int rankBlocks = B * (N >> 6);   // 64 rows per block
    nms_rank_kernel<<<rankBlocks + B, 1024, 0, stream>>>(scores, boxes, skeys,
                                                         sboxes, Mcnt, N,
                                                         rankBlocks);
    nms_mask_kernel<<<rankBlocks, 1024, 0, stream>>>(sboxes, Mcnt, mask, N);
    nms_scan_kernel<<<B, 512, 0, stream>>>(skeys, sboxes, Mcnt, mask, anchors,
                                           out, N, NS);
  } else {
    nms_fused_kernel<<<B, 1024, 0, stream>>>(scores, boxes, anchors, out, N, NS);
  }
}

// Round 8
// 95.305 us; speedup vs baseline: 1.5899x; 1.5899x over previous
//
#include <hip/hip_runtime.h>

static constexpr float kIouT = 0.35f;
static constexpr float kScoreT = 0.5f;
static constexpr int kMaxKeep = 512;

// Bit-exact mirror of the reference IoU (no FMA contraction).
__device__ __forceinline__ float iou_f(const float4 a, const float4 b) {
  float areaA = __fmul_rn(a.z - a.x, a.w - a.y);
  float areaB = __fmul_rn(b.z - b.x, b.w - b.y);
  float iy1 = fmaxf(a.x, b.x);
  float ix1 = fmaxf(a.y, b.y);
  float iy2 = fminf(a.z, b.z);
  float ix2 = fminf(a.w, b.w);
  float dy = fmaxf(iy2 - iy1, 0.0f);
  float dx = fmaxf(ix2 - ix1, 0.0f);
  float inter = __fmul_rn(dy, dx);
  float uni = (areaA + areaB) - inter;
  return (uni > 0.0f) ? __fdiv_rn(inter, uni) : 0.0f;
}

// 64-bit cross-lane pull with UNIFORM lane index (v_readlane, no LDS crossbar).
__device__ __forceinline__ unsigned long long rdlane64(unsigned long long v,
                                                       int l) {
  unsigned lo = (unsigned)__builtin_amdgcn_readlane((int)(unsigned)v, l);
  unsigned hi = (unsigned)__builtin_amdgcn_readlane((int)(unsigned)(v >> 32), l);
  return ((unsigned long long)hi << 32) | lo;
}

// ------- kernel 1 — rank (counting) sort of the VALID prefix (+count fold) ----
// [round-5 proven form] Blocks [0, rankBlocks): one wave per row. For valid
// row i: rank = #{j: s_j > s_i} + #{j: s_j==s_i, j<i}. Invalid j (s<=0.5) sort
// after every valid i, so counting over ALL j gives the stable-descending
// position. Blocks [rankBlocks, rankBlocks+B): per-image valid count -> Mcnt.
__global__ __launch_bounds__(256)
void nms_rank_kernel(const float* __restrict__ scores,
                     const float4* __restrict__ boxes,
                     unsigned long long* __restrict__ skeys,
                     float4* __restrict__ sboxes,
                     int* __restrict__ Mcnt, int N, int rankBlocks) {
  const int tid = threadIdx.x;
  const int lane = tid & 63;
  if ((int)blockIdx.x >= rankBlocks) {   // ---- count mode ----
    __shared__ int part[4];
    const int img = blockIdx.x - rankBlocks;
    const int wv = tid >> 6;
    const float4* sc4 = (const float4*)(scores + (size_t)img * N);
    int c = 0;
    for (int q = tid; q < (N >> 2); q += 256) {
      float4 v = sc4[q];
      c += (v.x > kScoreT) + (v.y > kScoreT) + (v.z > kScoreT) + (v.w > kScoreT);
    }
#pragma unroll
    for (int off = 1; off < 64; off <<= 1) c += __shfl_xor(c, off, 64);
    if (lane == 0) part[wv] = c;
    __syncthreads();
    if (tid == 0) Mcnt[img] = part[0] + part[1] + part[2] + part[3];
    return;
  }
  // ---- rank mode ----
  const int wid = (int)(((unsigned)blockIdx.x * blockDim.x + tid) >> 6);
  const int img = wid / N;
  const int row = wid - img * N;
  const float* sc = scores + (size_t)img * N;
  const float si = sc[row];
  if (!(si > kScoreT)) return;
  const float4* sc4 = (const float4*)sc;
  int cnt = 0;
  for (int q = lane; q < (N >> 2); q += 64) {   // coalesced, L1/L2-resident
    const float4 v = sc4[q];
    const int j = q << 2;
    cnt += (v.x > si) + (v.y > si) + (v.z > si) + (v.w > si);
    if (v.x == si && j < row) cnt++;
    if (v.y == si && j + 1 < row) cnt++;
    if (v.z == si && j + 2 < row) cnt++;
    if (v.w == si && j + 3 < row) cnt++;
  }
#pragma unroll
  for (int off = 1; off < 64; off <<= 1) cnt += __shfl_xor(cnt, off, 64);
  if (lane == 0) {
    skeys[(size_t)img * N + cnt] =
        ((unsigned long long)(~__float_as_uint(si)) << 32) | (unsigned)row;
    sboxes[(size_t)img * N + cnt] = boxes[(size_t)img * N + row];
  }
}

// ------------- kernel 2 — pairwise IoU suppression masks [round-5 form] ------
__global__ __launch_bounds__(256)
void nms_mask_kernel(const float4* __restrict__ sboxes,
                     const int* __restrict__ Mcnt,
                     unsigned long long* __restrict__ mask,
                     int N, int totalRows) {
  const int wid = (int)(((unsigned)blockIdx.x * blockDim.x + threadIdx.x) >> 6);
  const int lane = threadIdx.x & 63;
  if (wid >= totalRows) return;
  const int img = wid / N;
  const int row = wid - img * N;
  const int m = Mcnt[img];
  if (row >= m) return;
  const float4* sb = sboxes + (size_t)img * N;
  const float4 bi = sb[row];
  const int nw = (m + 63) >> 6;
  unsigned long long* mrow = mask + (size_t)wid * (size_t)(N >> 6);
  for (int w = row >> 6; w < nw; ++w) {
    int j = (w << 6) | lane;
    bool sup = false;
    if (j > row && j < m) sup = iou_f(bi, sb[j]) > kIouT;
    unsigned long long bm = __ballot(sup);
    if (lane == 0) mrow[w] = bm;
  }
}

// ------------- kernel 3 — single-wave scalar scan, 16-deep delta batches -----
// Serial keep-chain: pure SALU/readlane (~25cy/keep). Per keep-bearing chunk,
// kept rows' mask words are OR'd into lane-owned remv via a 16-deep batch of
// UNCONDITIONAL, clamp-indexed global loads (row indices in a statically
// unrolled array; exhausted slots repeat the last row -> idempotent OR).
// No conditional selects on the loads, so the compiler issues all 16
// back-to-back and waits once. __launch_bounds__(64,1) lifts the VGPR cap
// (round-5's 16-VGPR allocation serialized the batch -> ~700cy PER KEEP).
__global__ __launch_bounds__(64, 1)
void nms_scan_kernel(const unsigned long long* __restrict__ skeys,
                     const float4* __restrict__ sboxes,
                     const int* __restrict__ Mcnt,
                     const unsigned long long* __restrict__ mask,
                     const float* __restrict__ anchors,
                     float* __restrict__ out, int N, int NS) {
  __shared__ int keptlist[kMaxKeep];
  const int img = blockIdx.x;
  const int lane = threadIdx.x;
  int m = Mcnt[img];
  if (m > N) m = N;
  const int nw = (m + 63) >> 6;        // <= 64 since m <= 4096
  const int stride = N >> 6;
  const unsigned long long* mbase = mask + (size_t)img * (size_t)N * stride;
  const unsigned long long* kg = skeys + (size_t)img * N;
  const float4* sb = sboxes + (size_t)img * N;
  const float* an = anchors + (size_t)img * (size_t)N * 4;
  float* o = out + (size_t)img * NS * 7;

  int kept = 0;
  unsigned long long remv = 0ull;

  if (m > 0) {
    // diag prefetch pipeline (word cc of row cc*64+lane), 3 chunks ahead;
    // index clamped so tail loads are valid (values unused past nw).
    auto dgload = [&](int cc) -> unsigned long long {
      const int cl = cc < (nw - 1) ? cc : (nw - 1);
      return mbase[(size_t)((cl << 6) + lane) * stride + cl];
    };
    unsigned long long dg0 = dgload(0);
    unsigned long long dg1 = dgload(1);
    unsigned long long dg2 = dgload(2);

    for (int c = 0; c < nw && kept < NS; ++c) {
      const int cb = c << 6;
      unsigned long long local = rdlane64(remv, c);
      const int rem = m - cb;
      unsigned long long avail = ~local;
      if (rem < 64) avail &= (1ull << rem) - 1ull;
      unsigned long long keptbits = 0ull;
      const int keptbase = kept;
      // ---- serial greedy loop: pure scalar + readlane ----
      while (avail != 0ull && kept < NS) {
        const int b = (int)__builtin_ctzll(avail);
        keptbits |= 1ull << b;
        kept++;
        const unsigned long long rc = rdlane64(dg0, b);  // word c of row cb+b
        local |= rc;
        avail &= ~local;
        avail &= ~(1ull << b);
      }
      // rotate diag pipeline (issue next load before the delta waits)
      dg0 = dg1; dg1 = dg2; dg2 = dgload(c + 3);
      if (keptbits != 0ull) {
        // keptlist writes (off the serial chain)
        if (lane == 0) {
          unsigned long long kl = keptbits;
          int kc = keptbase;
          while (kl != 0ull) {
            const int b = (int)__builtin_ctzll(kl);
            kl &= kl - 1ull;
            keptlist[kc++] = cb + b;
          }
        }
        // ---- delta: 16-deep unconditional clamp-indexed load batches ----
        if (kept < NS || c + 1 < nw) {   // skip only if nothing future needs it
          const bool lok = (lane > c) && (lane < nw);
          unsigned long long kb = keptbits;
          while (kb != 0ull) {
            int bs[16];
            int bcur = (int)__builtin_ctzll(kb);
#pragma unroll
            for (int k = 0; k < 16; ++k) {
              if (kb != 0ull) {
                bcur = (int)__builtin_ctzll(kb);
                kb &= kb - 1ull;
              }
              bs[k] = bcur;            // duplicates when exhausted (idempotent)
            }
            unsigned long long t[16];
#pragma unroll
            for (int k = 0; k < 16; ++k)
              t[k] = mbase[(size_t)(cb + bs[k]) * stride + lane];
            unsigned long long acc = 0ull;
#pragma unroll
            for (int k = 0; k < 16; ++k) acc |= t[k];
            if (lok) remv |= acc;
          }
        }
      }
    }
  }

  __syncthreads();  // drain keptlist LDS writes for all lanes
  // parallel output over the wave
  for (int t = lane; t < kept; t += 64) {
    const int i = keptlist[t];
    const unsigned long long ki = kg[i];
    const float4 bi = sb[i];
    const unsigned idx = (unsigned)ki;
    float* row = o + t * 7;
    row[0] = __uint_as_float(~(unsigned)(ki >> 32));
    row[1] = bi.x; row[2] = bi.y; row[3] = bi.z; row[4] = bi.w;
    row[5] = an[idx * 4 + 2];
    row[6] = an[idx * 4 + 3];
  }
  for (int t = kept * 7 + lane; t < NS * 7; t += 64) o[t] = 0.0f;
}

// --------------- fallback: fused sort + on-the-fly scan (no d_ws) -------------
__global__ __launch_bounds__(1024)
void nms_fused_kernel(const float* __restrict__ scores,
                      const float4* __restrict__ boxes,
                      const float* __restrict__ anchors,
                      float* __restrict__ out, int N, int NS) {
  __shared__ unsigned long long keys[4096];
  __shared__ int s_m;
  if (N > 4096) return;
  const int img = blockIdx.x;
  const int tid = threadIdx.x;
  const float* sc = scores + (size_t)img * N;
  const float4* bx = boxes + (size_t)img * N;
  if (tid == 0) s_m = 0;
  __syncthreads();
  int cnt = 0;
  for (int i = tid; i < N; i += blockDim.x) {
    float s = sc[i];
    keys[i] = ((unsigned long long)(~__float_as_uint(s)) << 32) | (unsigned)i;
    if (s > kScoreT) cnt++;
  }
  if (cnt) atomicAdd(&s_m, cnt);
  __syncthreads();
  for (int k = 2; k <= N; k <<= 1) {
    for (int j = k >> 1; j > 0; j >>= 1) {
      for (int i = tid; i < N; i += blockDim.x) {
        int ixj = i ^ j;
        if (ixj > i) {
          unsigned long long a = keys[i];
          unsigned long long b = keys[ixj];
          bool up = ((i & k) == 0);
          if (up ? (a > b) : (a < b)) { keys[i] = b; keys[ixj] = a; }
        }
      }
      __syncthreads();
    }
  }
  if (tid >= 64) return;
  const int lane = tid;
  const int m = s_m;
  const int nw = (m + 63) >> 6;
  const float* an = anchors + (size_t)img * N * 4;
  float* o = out + (size_t)img * NS * 7;
  unsigned long long remv = 0ull;
  int kept = 0;
  for (int i = 0; i < m && kept < NS; ++i) {
    unsigned long long rw = __shfl(remv, i >> 6, 64);
    if ((rw >> (i & 63)) & 1ull) continue;
    unsigned long long ki = keys[i];
    float4 bi = bx[(unsigned)ki];
    if (lane == 0) {
      unsigned idx = (unsigned)ki;
      float* row = o + kept * 7;
      row[0] = __uint_as_float(~(unsigned)(ki >> 32));
      row[1] = bi.x; row[2] = bi.y; row[3] = bi.z; row[4] = bi.w;
      row[5] = an[idx * 4 + 2];
      row[6] = an[idx * 4 + 3];
    }
    kept++;
    for (int w2 = i >> 6; w2 < nw; ++w2) {
      int j = (w2 << 6) | lane;
      bool sup = false;
      if (j > i && j < m) sup = iou_f(bi, bx[(unsigned)keys[j]]) > kIouT;
      unsigned long long bm = __ballot(sup);
      if (lane == w2) remv |= bm;
    }
  }
  for (int t = kept * 7 + lane; t < NS * 7; t += 64) o[t] = 0.0f;
}

extern "C" void kernel_launch(void* const* d_in, const int* in_sizes, int n_in,
                              void* d_out, int out_size, void* d_ws, size_t ws_size,
                              hipStream_t stream) {
  const float* scores = (const float*)d_in[0];
  const float4* boxes = (const float4*)d_in[1];
  const float* anchors = (const float*)d_in[2];
  float* out = (float*)d_out;
  const int B = 8;
  const int N = in_sizes[0] / B;      // 4096 boxes/image
  const int NS = out_size / (B * 7);  // 300 samples

  const size_t nTot = (size_t)B * (size_t)N;
  const size_t keysB = nTot * 8;
  const size_t sboxB = nTot * 16;
  const size_t mcntB = 256;
  const size_t maskB = nTot * (size_t)(N >> 6) * 8;
  const size_t need = keysB + sboxB + mcntB + maskB;

  if (ws_size >= need && (N % 256) == 0 && N >= 256 && N <= 4096 &&
      NS <= kMaxKeep) {
    char* p = (char*)d_ws;
    unsigned long long* skeys = (unsigned long long*)p; p += keysB;
    float4* sboxes = (float4*)p;                         p += sboxB;
    int* Mcnt = (int*)p;                                 p += mcntB;
    unsigned long long* mask = (unsigned long long*)p;

    const int totalRows = B * N;
    const int rankBlocks = totalRows / 4;  // 256 thr = 4 waves per block
    nms_rank_kernel<<<rankBlocks + B, 256, 0, stream>>>(scores, boxes, skeys,
                                                        sboxes, Mcnt, N,
                                                        rankBlocks);
    nms_mask_kernel<<<rankBlocks, 256, 0, stream>>>(sboxes, Mcnt, mask, N,
                                                    totalRows);
    nms_scan_kernel<<<B, 64, 0, stream>>>(skeys, sboxes, Mcnt, mask, anchors,
                                          out, N, NS);
  } else {
    nms_fused_kernel<<<B, 1024, 0, stream>>>(scores, boxes, anchors, out, N, NS);
  }
}